// Round 5
// baseline (495.110 us; speedup 1.0000x reference)
//
#include <hip/hip_runtime.h>
#include <cstdint>
#include <cstddef>

typedef unsigned short u16;
typedef short v8s __attribute__((ext_vector_type(8)));
typedef float v4f __attribute__((ext_vector_type(4)));

constexpr int SEQ = 4096;
constexpr int FEAT = 2048;
constexpr int F3 = 6144;

// ---------- helpers ----------

__device__ __forceinline__ u16 f2bf(float f) {
  union { float f; uint32_t u; } v; v.f = f;
  uint32_t r = v.u + 0x7FFFu + ((v.u >> 16) & 1u);  // round-to-nearest-even
  return (u16)(r >> 16);
}

// async global->LDS, 16B per lane; lds dest is wave-uniform base (HW: base+lane*16)
__device__ __forceinline__ void gld_lds16(const u16* g, u16* l) {
  __builtin_amdgcn_global_load_lds(
      (const __attribute__((address_space(1))) void*)g,
      (__attribute__((address_space(3))) void*)l, 16, 0, 0);
}

// ---------- conversion / transpose ----------

__global__ void cvt_f32_bf16(const float* __restrict__ in, u16* __restrict__ out, int n8) {
  int i = blockIdx.x * 256 + threadIdx.x;
  if (i >= n8) return;
  const float4* p = (const float4*)in + (size_t)i * 2;
  float4 a = p[0], b = p[1];
  union { u16 s[8]; uint4 v; } u;
  u.s[0] = f2bf(a.x); u.s[1] = f2bf(a.y); u.s[2] = f2bf(a.z); u.s[3] = f2bf(a.w);
  u.s[4] = f2bf(b.x); u.s[5] = f2bf(b.y); u.s[6] = f2bf(b.z); u.s[7] = f2bf(b.w);
  *(uint4*)(out + (size_t)i * 8) = u.v;
}

__global__ void transp_f2b(const float* __restrict__ in, int ldin,
                           u16* __restrict__ out, int ldout) {
  __shared__ float tile[32][33];
  int c0 = blockIdx.x * 32, r0 = blockIdx.y * 32;
  int tx = threadIdx.x, ty = threadIdx.y;
#pragma unroll
  for (int p = 0; p < 4; ++p)
    tile[ty + 8 * p][tx] = in[(size_t)(r0 + ty + 8 * p) * ldin + c0 + tx];
  __syncthreads();
#pragma unroll
  for (int p = 0; p < 4; ++p)
    out[(size_t)(c0 + ty + 8 * p) * ldout + r0 + tx] = f2bf(tile[tx][ty + 8 * p]);
}

__global__ void transp_b2b(const u16* __restrict__ in, int ldin,
                           u16* __restrict__ out, int ldout) {
  __shared__ u16 tile[32][33];
  int c0 = blockIdx.x * 32, r0 = blockIdx.y * 32;
  int tx = threadIdx.x, ty = threadIdx.y;
#pragma unroll
  for (int p = 0; p < 4; ++p)
    tile[ty + 8 * p][tx] = in[(size_t)(r0 + ty + 8 * p) * ldin + c0 + tx];
  __syncthreads();
#pragma unroll
  for (int p = 0; p < 4; ++p)
    out[(size_t)(c0 + ty + 8 * p) * ldout + r0 + tx] = tile[tx][ty + 8 * p];
}

// ---------- GEMM: C[M,N] = A[M,K] * B[N,K]^T (bf16, k contiguous) ----------
// BM=BN=128, BK=64 as 2x(128x32) sub-tiles (4096 u16 each; element offsets).
// 256 thr = 4 waves, 2x2 of 64x64, 16x16x32 MFMA.
// LDS chunk swizzle (r4, verified: conflicts 1.26e7 -> 0): logical 16B chunk
// (row, col8) lives at col8' = (col8 + (row>>1))&3; staging inverts.
// MODE: 0 = normal grid (GEMM1)
//       1 = compact lower-triangular grid + split-K z=2, atomicAdd fp32 (GEMM2)
//       2 = causal balanced split-K z=4 (64-chunk granular), atomicAdd (GEMM3)
template<int OUTBF, int ADDB, int MODE>
__global__ __launch_bounds__(256) void gemm_bt(
    const u16* __restrict__ A, int lda,
    const u16* __restrict__ B, int ldb,
    void* __restrict__ Cv, int ldc,
    int K, const float* __restrict__ bias, float scale) {
  int bi, bj, ks, ke;
  if (MODE == 1) {
    const int t = blockIdx.x;
    bi = (int)((sqrtf(8.f * t + 1.f) - 1.f) * 0.5f);
    while ((bi + 1) * (bi + 2) / 2 <= t) ++bi;
    while (bi * (bi + 1) / 2 > t) --bi;
    bj = t - bi * (bi + 1) / 2;
    const int half = K >> 1;                 // 1024
    ks = blockIdx.z * half; ke = ks + half;
  } else if (MODE == 2) {
    bi = blockIdx.y; bj = blockIdx.x;
    const int nbk = 2 * (bi + 1);            // # of BK=64 chunks in causal K
    const int q = (nbk + 3) >> 2;            // chunks per z-slice (balanced)
    const int ca = blockIdx.z * q;
    const int cb = min(ca + q, nbk);
    if (ca >= cb) return;                    // uniform early-exit, no work
    ks = ca * 64; ke = cb * 64;
  } else {
    bi = blockIdx.y; bj = blockIdx.x;
    ks = 0; ke = K;
  }
  const int i0 = bi * 128, j0 = bj * 128;

  __shared__ u16 As[128 * 64];   // sub-tile s at element offset s*4096
  __shared__ u16 Bs[128 * 64];

  const int t = threadIdx.x;
  const int w = t >> 6, l = t & 63;
  const int wr = w >> 1, wc = w & 1;
  const int lm = l & 15, lq = l >> 4;
  // swizzled col8' for fragment reads: (R>>1)&3 == (lm>>1)&3 for all mi/wr
  const int lqs = ((lq + (lm >> 1)) & 3) * 8;  // element offset within row

  v4f acc[4][4];
#pragma unroll
  for (int a = 0; a < 4; ++a)
#pragma unroll
    for (int b = 0; b < 4; ++b)
      acc[a][b] = v4f{0.f, 0.f, 0.f, 0.f};

  // staging: thread t handles chunks c=t and c=t+256 of each 128x32 sub-tile.
  // chunk c -> LDS bytes [c*16, c*16+16) (fixed by global_load_lds);
  // global source: row = c>>2, col8 = ((c&3) - ((c>>3)&3)) & 3  (swizzle inverse)
  const int c1 = t + 256;
  const int r0c = t >> 2, o0 = ((((t & 3) - ((t >> 3) & 3)) & 3)) * 8;
  const int r1c = c1 >> 2, o1 = ((((c1 & 3) - ((c1 >> 3) & 3)) & 3)) * 8;
  const u16* Ag0 = A + (size_t)(i0 + r0c) * lda + o0;
  const u16* Ag1 = A + (size_t)(i0 + r1c) * lda + o1;
  const u16* Bg0 = B + (size_t)(j0 + r0c) * ldb + o0;
  const u16* Bg1 = B + (size_t)(j0 + r1c) * ldb + o1;
  u16* Al0 = &As[w * 512];
  u16* Al1 = &As[w * 512 + 2048];
  u16* Bl0 = &Bs[w * 512];
  u16* Bl1 = &Bs[w * 512 + 2048];

  for (int k0 = ks; k0 < ke; k0 += 64) {
    gld_lds16(Ag0 + k0, Al0);
    gld_lds16(Ag1 + k0, Al1);
    gld_lds16(Bg0 + k0, Bl0);
    gld_lds16(Bg1 + k0, Bl1);
    gld_lds16(Ag0 + k0 + 32, Al0 + 4096);
    gld_lds16(Ag1 + k0 + 32, Al1 + 4096);
    gld_lds16(Bg0 + k0 + 32, Bl0 + 4096);
    gld_lds16(Bg1 + k0 + 32, Bl1 + 4096);
    __syncthreads();  // drains vmcnt(0): staged data visible

#pragma unroll
    for (int s = 0; s < 2; ++s) {
      v8s af[4], bfr[4];
#pragma unroll
      for (int mi = 0; mi < 4; ++mi)
        af[mi] = *(const v8s*)&As[s * 4096 + (wr * 64 + mi * 16 + lm) * 32 + lqs];
#pragma unroll
      for (int ni = 0; ni < 4; ++ni)
        bfr[ni] = *(const v8s*)&Bs[s * 4096 + (wc * 64 + ni * 16 + lm) * 32 + lqs];
#pragma unroll
      for (int mi = 0; mi < 4; ++mi)
#pragma unroll
        for (int ni = 0; ni < 4; ++ni)
          acc[mi][ni] = __builtin_amdgcn_mfma_f32_16x16x32_bf16(af[mi], bfr[ni], acc[mi][ni], 0, 0, 0);
    }
    __syncthreads();  // LDS reads done before next stage
  }

  // epilogue: C/D layout col=lane&15, row=quad*4+reg [m89-verified]
#pragma unroll
  for (int mi = 0; mi < 4; ++mi) {
#pragma unroll
    for (int ni = 0; ni < 4; ++ni) {
      const int cc = j0 + wc * 64 + ni * 16 + lm;
      const float badd = ADDB ? bias[cc] : 0.f;
#pragma unroll
      for (int r = 0; r < 4; ++r) {
        const int rr = i0 + wr * 64 + mi * 16 + lq * 4 + r;
        float v = acc[mi][ni][r] * scale + badd;
        if (OUTBF)           ((u16*)Cv)[(size_t)rr * ldc + cc] = f2bf(v);
        else if (MODE >= 1)  atomicAdd((float*)Cv + (size_t)rr * ldc + cc, v);
        else                 ((float*)Cv)[(size_t)rr * ldc + cc] = v;
      }
    }
  }
}

// ---------- row softmax with causal + padding mask ----------
__global__ __launch_bounds__(256) void softmax_rows(
    const float* __restrict__ S, u16* __restrict__ att, const int* __restrict__ npad_p) {
  const int i = blockIdx.x;
  const int np = *npad_p;
  const int kend = ((i >> 7) + 1) << 7;
  const float* row = S + (size_t)i * SEQ;
  u16* arow = att + (size_t)i * SEQ;
  const int t = threadIdx.x;

  float m = -3.0e38f, s = 0.f;
  for (int j = np + t; j <= i; j += 256) {
    float v = row[j];
    if (v > m) { s = s * __expf(m - v) + 1.f; m = v; }
    else       { s += __expf(v - m); }
  }
#pragma unroll
  for (int off = 32; off > 0; off >>= 1) {
    float mo = __shfl_xor(m, off);
    float so = __shfl_xor(s, off);
    float M = fmaxf(m, mo);
    s = s * __expf(m - M) + so * __expf(mo - M);
    m = M;
  }
  __shared__ float sm[4], ss[4];
  const int w = t >> 6, l = t & 63;
  if (l == 0) { sm[w] = m; ss[w] = s; }
  __syncthreads();
  const float M = fmaxf(fmaxf(sm[0], sm[1]), fmaxf(sm[2], sm[3]));
  const float Ssum = ss[0] * __expf(sm[0] - M) + ss[1] * __expf(sm[1] - M) +
                     ss[2] * __expf(sm[2] - M) + ss[3] * __expf(sm[3] - M);
  const float inv = 1.f / Ssum;  // padded rows masked to 0 below; inv unused there

  for (int j0b = t * 8; j0b < kend; j0b += 2048) {
    union { u16 s8[8]; uint4 v; } u;
#pragma unroll
    for (int q = 0; q < 8; ++q) {
      const int j = j0b + q;
      float a = 0.f;
      if (j >= np && j <= i) a = __expf(row[j] - M) * inv;
      u.s8[q] = f2bf(a);
    }
    *(uint4*)(arow + j0b) = u.v;
  }
}

// ---------- launch ----------

extern "C" void kernel_launch(void* const* d_in, const int* in_sizes, int n_in,
                              void* d_out, int out_size, void* d_ws, size_t ws_size,
                              hipStream_t stream) {
  const float* x = (const float*)d_in[0];
  const float* W = (const float*)d_in[1];
  const float* b = (const float*)d_in[2];
  const int* npad = (const int*)d_in[3];
  float* out = (float*)d_out;

  // workspace: [xb 16MB | Wt 24MB] reused as att 32MB ][ qkvb 48MB ][ vt 16MB ][ sc 64MB ]
  char* p = (char*)d_ws;
  u16* xb = (u16*)p;
  u16* Wt = (u16*)(p + (size_t)SEQ * FEAT * 2);
  u16* att = (u16*)p;
  p += (size_t)SEQ * FEAT * 2 + (size_t)F3 * FEAT * 2;
  u16* qkvb = (u16*)p;  p += (size_t)SEQ * F3 * 2;
  u16* vt   = (u16*)p;  p += (size_t)FEAT * SEQ * 2;
  float* sc = (float*)p; p += (size_t)SEQ * SEQ * 4;
  if (ws_size < (size_t)(p - (char*)d_ws)) return;

  const float scale = 0.02209708691207961f;  // 1/sqrt(2048)

  // zero the split-K atomic destinations up front (both idle until their GEMMs)
  hipMemsetAsync(d_out, 0, (size_t)SEQ * FEAT * sizeof(float), stream);
  hipMemsetAsync(sc, 0, (size_t)SEQ * SEQ * sizeof(float), stream);

  cvt_f32_bf16<<<SEQ * FEAT / 8 / 256, 256, 0, stream>>>(x, xb, SEQ * FEAT / 8);
  transp_f2b<<<dim3(F3 / 32, FEAT / 32), dim3(32, 8), 0, stream>>>(W, F3, Wt, FEAT);
  // qkv = x @ W + b (bf16)
  gemm_bt<1, 1, 0><<<dim3(F3 / 128, SEQ / 128), 256, 0, stream>>>(
      xb, FEAT, Wt, FEAT, (void*)qkvb, F3, FEAT, b, 1.0f);
  transp_b2b<<<dim3(FEAT / 32, SEQ / 32), dim3(32, 8), 0, stream>>>(
      qkvb + 2 * FEAT, F3, vt, SEQ);
  // scores = (q @ k^T) / sqrt(F): triangular grid x split-K=2, atomic fp32
  gemm_bt<0, 0, 1><<<dim3(32 * 33 / 2, 1, 2), 256, 0, stream>>>(
      qkvb, F3, qkvb + FEAT, F3, (void*)sc, SEQ, FEAT, nullptr, scale);
  softmax_rows<<<SEQ, 256, 0, stream>>>(sc, att, npad);
  // out = att @ v: balanced 4-way causal split-K, atomic fp32
  gemm_bt<0, 0, 2><<<dim3(FEAT / 128, SEQ / 128, 4), 256, 0, stream>>>(
      att, SEQ, vt, SEQ, (void*)out, FEAT, 0, nullptr, 1.0f);
}

// Round 6
// 411.838 us; speedup vs baseline: 1.2022x; 1.2022x over previous
//
#include <hip/hip_runtime.h>
#include <cstdint>
#include <cstddef>

typedef unsigned short u16;
typedef short v8s __attribute__((ext_vector_type(8)));
typedef float v4f __attribute__((ext_vector_type(4)));

constexpr int SEQ = 4096;
constexpr int FEAT = 2048;
constexpr int F3 = 6144;

// ---------- helpers ----------

__device__ __forceinline__ u16 f2bf(float f) {
  union { float f; uint32_t u; } v; v.f = f;
  uint32_t r = v.u + 0x7FFFu + ((v.u >> 16) & 1u);  // round-to-nearest-even
  return (u16)(r >> 16);
}

__device__ __forceinline__ float bf2f(u16 s) {
  union { uint32_t u; float f; } v; v.u = ((uint32_t)s) << 16;
  return v.f;
}

// async global->LDS, 16B per lane; lds dest is wave-uniform base (HW: base+lane*16)
__device__ __forceinline__ void gld_lds16(const u16* g, u16* l) {
  __builtin_amdgcn_global_load_lds(
      (const __attribute__((address_space(1))) void*)g,
      (__attribute__((address_space(3))) void*)l, 16, 0, 0);
}

// ---------- conversion / transpose ----------

__global__ void cvt_f32_bf16(const float* __restrict__ in, u16* __restrict__ out, int n8) {
  int i = blockIdx.x * 256 + threadIdx.x;
  if (i >= n8) return;
  const float4* p = (const float4*)in + (size_t)i * 2;
  float4 a = p[0], b = p[1];
  union { u16 s[8]; uint4 v; } u;
  u.s[0] = f2bf(a.x); u.s[1] = f2bf(a.y); u.s[2] = f2bf(a.z); u.s[3] = f2bf(a.w);
  u.s[4] = f2bf(b.x); u.s[5] = f2bf(b.y); u.s[6] = f2bf(b.z); u.s[7] = f2bf(b.w);
  *(uint4*)(out + (size_t)i * 8) = u.v;
}

__global__ void transp_f2b(const float* __restrict__ in, int ldin,
                           u16* __restrict__ out, int ldout) {
  __shared__ float tile[32][33];
  int c0 = blockIdx.x * 32, r0 = blockIdx.y * 32;
  int tx = threadIdx.x, ty = threadIdx.y;
#pragma unroll
  for (int p = 0; p < 4; ++p)
    tile[ty + 8 * p][tx] = in[(size_t)(r0 + ty + 8 * p) * ldin + c0 + tx];
  __syncthreads();
#pragma unroll
  for (int p = 0; p < 4; ++p)
    out[(size_t)(c0 + ty + 8 * p) * ldout + r0 + tx] = f2bf(tile[tx][ty + 8 * p]);
}

__global__ void transp_b2b(const u16* __restrict__ in, int ldin,
                           u16* __restrict__ out, int ldout) {
  __shared__ u16 tile[32][33];
  int c0 = blockIdx.x * 32, r0 = blockIdx.y * 32;
  int tx = threadIdx.x, ty = threadIdx.y;
#pragma unroll
  for (int p = 0; p < 4; ++p)
    tile[ty + 8 * p][tx] = in[(size_t)(r0 + ty + 8 * p) * ldin + c0 + tx];
  __syncthreads();
#pragma unroll
  for (int p = 0; p < 4; ++p)
    out[(size_t)(c0 + ty + 8 * p) * ldout + r0 + tx] = tile[tx][ty + 8 * p];
}

// ---------- GEMM: C[M,N] = A[M,K] * B[N,K]^T (bf16, k contiguous) ----------
// BM=BN=128, BK=64 as 2x(128x32) sub-tiles (4096 u16 each; element offsets).
// 256 thr = 4 waves, 2x2 of 64x64, 16x16x32 MFMA.
// LDS chunk swizzle (r4, verified: conflicts 1.26e7 -> 0): logical 16B chunk
// (row, col8) lives at col8' = (col8 + (row>>1))&3; staging inverts.
// MODE: 0 = normal grid (GEMM1)
//       1 = compact lower-triangular grid, split-K z=2 into DISJOINT buffers:
//           z-slice writes bf16 C at Cv + z*SEQ*SEQ (plain stores, no atomics)
//       2 = causal split-K z=2 (half=(bi+1)*64), atomicAdd fp32 (GEMM3, r4 cfg)
template<int OUTBF, int ADDB, int MODE>
__global__ __launch_bounds__(256) void gemm_bt(
    const u16* __restrict__ A, int lda,
    const u16* __restrict__ B, int ldb,
    void* __restrict__ Cv, int ldc,
    int K, const float* __restrict__ bias, float scale) {
  int bi, bj, ks, ke;
  if (MODE == 1) {
    const int t = blockIdx.x;
    bi = (int)((sqrtf(8.f * t + 1.f) - 1.f) * 0.5f);
    while ((bi + 1) * (bi + 2) / 2 <= t) ++bi;
    while (bi * (bi + 1) / 2 > t) --bi;
    bj = t - bi * (bi + 1) / 2;
    const int half = K >> 1;                 // 1024
    ks = blockIdx.z * half; ke = ks + half;
    Cv = (void*)((u16*)Cv + (size_t)blockIdx.z * SEQ * SEQ);  // disjoint buffer
  } else if (MODE == 2) {
    bi = blockIdx.y; bj = blockIdx.x;
    const int half = (bi + 1) * 64;          // kend/2, multiple of 64
    ks = blockIdx.z * half; ke = ks + half;
  } else {
    bi = blockIdx.y; bj = blockIdx.x;
    ks = 0; ke = K;
  }
  const int i0 = bi * 128, j0 = bj * 128;

  __shared__ u16 As[128 * 64];   // sub-tile s at element offset s*4096
  __shared__ u16 Bs[128 * 64];

  const int t = threadIdx.x;
  const int w = t >> 6, l = t & 63;
  const int wr = w >> 1, wc = w & 1;
  const int lm = l & 15, lq = l >> 4;
  // swizzled col8' for fragment reads: (R>>1)&3 == (lm>>1)&3 for all mi/wr
  const int lqs = ((lq + (lm >> 1)) & 3) * 8;  // element offset within row

  v4f acc[4][4];
#pragma unroll
  for (int a = 0; a < 4; ++a)
#pragma unroll
    for (int b = 0; b < 4; ++b)
      acc[a][b] = v4f{0.f, 0.f, 0.f, 0.f};

  // staging: thread t handles chunks c=t and c=t+256 of each 128x32 sub-tile.
  // chunk c -> LDS bytes [c*16, c*16+16) (fixed by global_load_lds);
  // global source: row = c>>2, col8 = ((c&3) - ((c>>3)&3)) & 3  (swizzle inverse)
  const int c1 = t + 256;
  const int r0c = t >> 2, o0 = ((((t & 3) - ((t >> 3) & 3)) & 3)) * 8;
  const int r1c = c1 >> 2, o1 = ((((c1 & 3) - ((c1 >> 3) & 3)) & 3)) * 8;
  const u16* Ag0 = A + (size_t)(i0 + r0c) * lda + o0;
  const u16* Ag1 = A + (size_t)(i0 + r1c) * lda + o1;
  const u16* Bg0 = B + (size_t)(j0 + r0c) * ldb + o0;
  const u16* Bg1 = B + (size_t)(j0 + r1c) * ldb + o1;
  u16* Al0 = &As[w * 512];
  u16* Al1 = &As[w * 512 + 2048];
  u16* Bl0 = &Bs[w * 512];
  u16* Bl1 = &Bs[w * 512 + 2048];

  for (int k0 = ks; k0 < ke; k0 += 64) {
    gld_lds16(Ag0 + k0, Al0);
    gld_lds16(Ag1 + k0, Al1);
    gld_lds16(Bg0 + k0, Bl0);
    gld_lds16(Bg1 + k0, Bl1);
    gld_lds16(Ag0 + k0 + 32, Al0 + 4096);
    gld_lds16(Ag1 + k0 + 32, Al1 + 4096);
    gld_lds16(Bg0 + k0 + 32, Bl0 + 4096);
    gld_lds16(Bg1 + k0 + 32, Bl1 + 4096);
    __syncthreads();  // drains vmcnt(0): staged data visible

#pragma unroll
    for (int s = 0; s < 2; ++s) {
      v8s af[4], bfr[4];
#pragma unroll
      for (int mi = 0; mi < 4; ++mi)
        af[mi] = *(const v8s*)&As[s * 4096 + (wr * 64 + mi * 16 + lm) * 32 + lqs];
#pragma unroll
      for (int ni = 0; ni < 4; ++ni)
        bfr[ni] = *(const v8s*)&Bs[s * 4096 + (wc * 64 + ni * 16 + lm) * 32 + lqs];
#pragma unroll
      for (int mi = 0; mi < 4; ++mi)
#pragma unroll
        for (int ni = 0; ni < 4; ++ni)
          acc[mi][ni] = __builtin_amdgcn_mfma_f32_16x16x32_bf16(af[mi], bfr[ni], acc[mi][ni], 0, 0, 0);
    }
    __syncthreads();  // LDS reads done before next stage
  }

  // epilogue: C/D layout col=lane&15, row=quad*4+reg [m89-verified]
#pragma unroll
  for (int mi = 0; mi < 4; ++mi) {
#pragma unroll
    for (int ni = 0; ni < 4; ++ni) {
      const int cc = j0 + wc * 64 + ni * 16 + lm;
      const float badd = ADDB ? bias[cc] : 0.f;
#pragma unroll
      for (int r = 0; r < 4; ++r) {
        const int rr = i0 + wr * 64 + mi * 16 + lq * 4 + r;
        float v = acc[mi][ni][r] * scale + badd;
        if (OUTBF)           ((u16*)Cv)[(size_t)rr * ldc + cc] = f2bf(v);
        else if (MODE == 2)  atomicAdd((float*)Cv + (size_t)rr * ldc + cc, v);
        else                 ((float*)Cv)[(size_t)rr * ldc + cc] = v;
      }
    }
  }
}

// ---------- row softmax with causal + padding mask ----------
// scores come as two bf16 split-K partials: s(i,j) = sc0[i,j] + sc1[i,j]
__global__ __launch_bounds__(256) void softmax_rows(
    const u16* __restrict__ S0, const u16* __restrict__ S1,
    u16* __restrict__ att, const int* __restrict__ npad_p) {
  const int i = blockIdx.x;
  const int np = *npad_p;
  const int kend = ((i >> 7) + 1) << 7;
  const u16* r0 = S0 + (size_t)i * SEQ;
  const u16* r1 = S1 + (size_t)i * SEQ;
  u16* arow = att + (size_t)i * SEQ;
  const int t = threadIdx.x;

  float m = -3.0e38f, s = 0.f;
  for (int j = np + t; j <= i; j += 256) {
    float v = bf2f(r0[j]) + bf2f(r1[j]);
    if (v > m) { s = s * __expf(m - v) + 1.f; m = v; }
    else       { s += __expf(v - m); }
  }
#pragma unroll
  for (int off = 32; off > 0; off >>= 1) {
    float mo = __shfl_xor(m, off);
    float so = __shfl_xor(s, off);
    float M = fmaxf(m, mo);
    s = s * __expf(m - M) + so * __expf(mo - M);
    m = M;
  }
  __shared__ float sm[4], ss[4];
  const int w = t >> 6, l = t & 63;
  if (l == 0) { sm[w] = m; ss[w] = s; }
  __syncthreads();
  const float M = fmaxf(fmaxf(sm[0], sm[1]), fmaxf(sm[2], sm[3]));
  const float Ssum = ss[0] * __expf(sm[0] - M) + ss[1] * __expf(sm[1] - M) +
                     ss[2] * __expf(sm[2] - M) + ss[3] * __expf(sm[3] - M);
  const float inv = 1.f / Ssum;  // padded rows masked to 0 below; inv unused there

  for (int j0b = t * 8; j0b < kend; j0b += 2048) {
    union { u16 s8[8]; uint4 v; } u;
#pragma unroll
    for (int q = 0; q < 8; ++q) {
      const int j = j0b + q;
      float a = 0.f;
      if (j >= np && j <= i)
        a = __expf(bf2f(r0[j]) + bf2f(r1[j]) - M) * inv;
      u.s8[q] = f2bf(a);
    }
    *(uint4*)(arow + j0b) = u.v;
  }
}

// ---------- launch ----------

extern "C" void kernel_launch(void* const* d_in, const int* in_sizes, int n_in,
                              void* d_out, int out_size, void* d_ws, size_t ws_size,
                              hipStream_t stream) {
  const float* x = (const float*)d_in[0];
  const float* W = (const float*)d_in[1];
  const float* b = (const float*)d_in[2];
  const int* npad = (const int*)d_in[3];
  float* out = (float*)d_out;

  // workspace (168 MB total, same as r4):
  // [xb 16MB | Wt 24MB] reused as att 32MB ][ qkvb 48MB ][ vt 16MB ][ sc0 32MB | sc1 32MB ]
  char* p = (char*)d_ws;
  u16* xb = (u16*)p;
  u16* Wt = (u16*)(p + (size_t)SEQ * FEAT * 2);
  u16* att = (u16*)p;
  p += (size_t)SEQ * FEAT * 2 + (size_t)F3 * FEAT * 2;
  u16* qkvb = (u16*)p;  p += (size_t)SEQ * F3 * 2;
  u16* vt   = (u16*)p;  p += (size_t)FEAT * SEQ * 2;
  u16* sc0  = (u16*)p;  p += (size_t)SEQ * SEQ * 2;   // bf16 split-K partial 0
  u16* sc1  = (u16*)p;  p += (size_t)SEQ * SEQ * 2;   // bf16 split-K partial 1
  if (ws_size < (size_t)(p - (char*)d_ws)) return;

  const float scale = 0.02209708691207961f;  // 1/sqrt(2048)

  // zero d_out (GEMM3 split-K atomically accumulates into it)
  hipMemsetAsync(d_out, 0, (size_t)SEQ * FEAT * sizeof(float), stream);

  cvt_f32_bf16<<<SEQ * FEAT / 8 / 256, 256, 0, stream>>>(x, xb, SEQ * FEAT / 8);
  transp_f2b<<<dim3(F3 / 32, FEAT / 32), dim3(32, 8), 0, stream>>>(W, F3, Wt, FEAT);
  // qkv = x @ W + b (bf16)
  gemm_bt<1, 1, 0><<<dim3(F3 / 128, SEQ / 128), 256, 0, stream>>>(
      xb, FEAT, Wt, FEAT, (void*)qkvb, F3, FEAT, b, 1.0f);
  transp_b2b<<<dim3(FEAT / 32, SEQ / 32), dim3(32, 8), 0, stream>>>(
      qkvb + 2 * FEAT, F3, vt, SEQ);
  // scores = (q @ k^T) / sqrt(F): triangular grid x split-K=2 -> sc0/sc1 bf16
  gemm_bt<1, 0, 1><<<dim3(32 * 33 / 2, 1, 2), 256, 0, stream>>>(
      qkvb, F3, qkvb + FEAT, F3, (void*)sc0, SEQ, FEAT, nullptr, scale);
  softmax_rows<<<SEQ, 256, 0, stream>>>(sc0, sc1, att, npad);
  // out = att @ v: causal split-K=2, atomic fp32 (r4 config)
  gemm_bt<0, 0, 2><<<dim3(FEAT / 128, SEQ / 128, 2), 256, 0, stream>>>(
      att, SEQ, vt, SEQ, (void*)out, FEAT, 0, nullptr, 1.0f);
}